// Round 9
// baseline (323.697 us; speedup 1.0000x reference)
//
#include <hip/hip_runtime.h>
#include <hip/hip_bf16.h>

// GraphSAGE 3-layer forward, MI355X. Round 9:
//  - agg+GEMM fused per 128-node tile (agg -> LDS tile -> MFMA from LDS):
//    hA/hB intermediates eliminated, 8 -> 6 dispatches, no global sync needed
//    (agg rows n feed only GEMM rows n = same block).
//  - 2-node interleaved gather pipeline (32 outstanding loads) + adj prefetch
//    to compensate for the smaller fused grid (391 blocks).
//  - dist_cast / build||gemm0 / final unchanged from R8.

typedef __attribute__((ext_vector_type(8))) short bf16x8;
typedef __attribute__((ext_vector_type(4))) float f32x4;

#define NPB 128            // nodes per bucket (bucket = dst >> 7)
#define BCAP 2560          // per-bucket staging capacity
#define EPB 8192           // edges per distribute block
#define EPT 32             // edges per thread (256 thr)
#define CPAD 16            // global counter stride in ints (64B line each)
#define HS_STRIDE_U32 68   // LDS tile row stride in uints (136 bf16 = 272B, 16B-aligned, 2-way-max banks)

__device__ __forceinline__ unsigned short f2bf(float f) {
    unsigned int u = __builtin_bit_cast(unsigned int, f);
    u += 0x7fffu + ((u >> 16) & 1u);           // round-to-nearest-even
    return (unsigned short)(u >> 16);
}
__device__ __forceinline__ float bf2f(unsigned int bits16) {
    return __builtin_bit_cast(float, bits16 << 16);
}

// ---------------- fused: CSR phase A (distribute) + bf16 casts ----------------

__global__ __launch_bounds__(256) void dist_cast_kernel(
        const int* __restrict__ dst, const int* __restrict__ srcv,
        int* __restrict__ gcnt, unsigned int* __restrict__ staging, int E, int NBc,
        const float* __restrict__ x,
        const float* p0, const float* p1, const float* p2,
        const float* p3, const float* p4, const float* p5,
        unsigned short* __restrict__ xbf, unsigned short* __restrict__ wbf,
        int xpairs, int distBlocks) {
    __shared__ unsigned int stage[EPB];      // 32KB
    __shared__ int hist[400];
    __shared__ int lstart[400];
    __shared__ int gbase[400];
    __shared__ int scanbuf[256];
    int t = threadIdx.x;

    if (blockIdx.x >= distBlocks) {
        int bid = blockIdx.x - distBlocks;
        int xblocks = (xpairs + 255) / 256;
        if (bid < xblocks) {
            int i = bid * 256 + t;
            if (i < xpairs) {
                float2 v = ((const float2*)x)[i];
                unsigned int p = (unsigned int)f2bf(v.x) | ((unsigned int)f2bf(v.y) << 16);
                ((unsigned int*)xbf)[i] = p;
            }
        } else {
            int w = (bid - xblocks) * 256 + t;
            if (w < 40960) {
                const float* src;
                int local;
                if      (w < 8192)  { src = p0; local = w; }
                else if (w < 16384) { src = p1; local = w - 8192; }
                else if (w < 24576) { src = p2; local = w - 16384; }
                else if (w < 32768) { src = p3; local = w - 24576; }
                else if (w < 36864) { src = p4; local = w - 32768; }
                else                { src = p5; local = w - 36864; }
                float2 v = ((const float2*)src)[local];
                unsigned int p = (unsigned int)f2bf(v.x) | ((unsigned int)f2bf(v.y) << 16);
                ((unsigned int*)wbf)[w] = p;
            }
        }
        return;
    }

    int e0 = blockIdx.x * EPB;
    unsigned int w[EPT];

    for (int b = t; b < NBc + 1; b += 256) hist[b] = 0;
    __syncthreads();

#pragma unroll
    for (int i = 0; i < EPT; ++i) {
        int e = e0 + i * 256 + t;
        unsigned int word = 0xFFFFFFFFu;
        if (e < E) word = ((unsigned int)dst[e] << 16) | (unsigned int)srcv[e];
        w[i] = word;
        int b = (int)(word >> 23); if (b > NBc) b = NBc;
        atomicAdd(&hist[b], 1);
    }
    __syncthreads();

    int b0 = 2 * t, b1 = 2 * t + 1;
    int h0 = (b0 <= NBc) ? hist[b0] : 0;
    int h1 = (b1 <= NBc) ? hist[b1] : 0;
    int pair = h0 + h1;
    scanbuf[t] = pair;
    __syncthreads();
    for (int off = 1; off < 256; off <<= 1) {
        int v = (t >= off) ? scanbuf[t - off] : 0;
        __syncthreads();
        scanbuf[t] += v;
        __syncthreads();
    }
    int excl = scanbuf[t] - pair;
    if (b0 <= NBc) lstart[b0] = excl;
    if (b1 <= NBc) lstart[b1] = excl + h0;
    __syncthreads();

    for (int b = t; b < NBc; b += 256) {
        int h = hist[b];
        gbase[b] = h ? atomicAdd(&gcnt[b * CPAD], h) : 0;
    }
    for (int b = t; b < NBc + 1; b += 256) hist[b] = lstart[b];
    __syncthreads();

#pragma unroll
    for (int i = 0; i < EPT; ++i) {
        unsigned int word = w[i];
        int b = (int)(word >> 23); if (b > NBc) b = NBc;
        int p = atomicAdd(&hist[b], 1);
        stage[p] = word;
    }
    __syncthreads();

    int total = lstart[NBc];
    for (int i = t; i < total; i += 256) {
        unsigned int word = stage[i];
        int b = (int)(word >> 23);
        int gpos = gbase[b] + (i - lstart[b]);
        staging[(size_t)b * BCAP + gpos] = word;
    }
}

// ---------------- GEMM tile helper (global A): used by build||gemm0 ----------------

__device__ __forceinline__ void gemm_tile(const unsigned short* __restrict__ H,
                                          const unsigned short* __restrict__ Wl,
                                          const unsigned short* __restrict__ Wr,
                                          unsigned short* __restrict__ CL,
                                          unsigned short* __restrict__ CR,
                                          int bx, int y, int half, int ldC, int N) {
    int wave = threadIdx.x >> 6;
    int lane = threadIdx.x & 63;
    int l15 = lane & 15, quad = lane >> 4;
    const unsigned short* W = (y < half) ? Wl : Wr;
    unsigned short* Cout = (y < half) ? CL : CR;
    int slab = (y < half) ? y : y - half;
    int wrow0 = slab * 64;
    int col0 = slab * 64;
    int m0 = bx * 128 + wave * 32;

    int r0 = m0 + l15;      if (r0 > N - 1) r0 = N - 1;
    int r1 = m0 + 16 + l15; if (r1 > N - 1) r1 = N - 1;
    const bf16x8* A0 = (const bf16x8*)(H + (size_t)r0 * 128);
    const bf16x8* A1 = (const bf16x8*)(H + (size_t)r1 * 128);

    f32x4 acc[2][4] = {};
#pragma unroll
    for (int ks = 0; ks < 4; ++ks) {
        int vidx = ks * 4 + quad;
        bf16x8 a0 = A0[vidx];
        bf16x8 a1 = A1[vidx];
#pragma unroll
        for (int j = 0; j < 4; ++j) {
            const bf16x8* B = (const bf16x8*)(W + (size_t)(wrow0 + j * 16 + l15) * 128);
            bf16x8 b = B[vidx];
            acc[0][j] = __builtin_amdgcn_mfma_f32_16x16x32_bf16(a0, b, acc[0][j], 0, 0, 0);
            acc[1][j] = __builtin_amdgcn_mfma_f32_16x16x32_bf16(a1, b, acc[1][j], 0, 0, 0);
        }
    }

#pragma unroll
    for (int i = 0; i < 2; ++i)
#pragma unroll
        for (int j = 0; j < 4; ++j)
#pragma unroll
            for (int r = 0; r < 4; ++r) {
                int row = m0 + i * 16 + quad * 4 + r;
                if (row < N) {
                    int col = col0 + j * 16 + l15;
                    Cout[(size_t)row * ldC + col] = f2bf(acc[i][j][r]);
                }
            }
}

// ---------------- merged: CSR phase B (build) || gemm0 ----------------

__global__ __launch_bounds__(256) void build_gemm0_kernel(
        const unsigned int* __restrict__ staging, const int* __restrict__ gcnt,
        int* __restrict__ row_ptr, int* __restrict__ adj, int N, int NBc,
        const unsigned short* __restrict__ xbf,
        const unsigned short* __restrict__ wl0, const unsigned short* __restrict__ wr0,
        unsigned short* __restrict__ CL, unsigned short* __restrict__ CR,
        int gemmRows) {
    __shared__ int lstart[400];
    __shared__ int scanbuf[256];
    __shared__ int hist[NPB];
    __shared__ int scn[NPB];
    int t = threadIdx.x;

    if (blockIdx.x >= (unsigned)NBc) {
        int g = blockIdx.x - NBc;
        gemm_tile(xbf, wl0, wr0, CL, CR, g % gemmRows, g / gemmRows, 2, 128, N);
        return;
    }
    int b = blockIdx.x;

    int b0 = 2 * t, b1 = 2 * t + 1;
    int h0 = (b0 < NBc) ? gcnt[b0 * CPAD] : 0;
    int h1 = (b1 < NBc) ? gcnt[b1 * CPAD] : 0;
    int pair = h0 + h1;
    scanbuf[t] = pair;
    __syncthreads();
    for (int off = 1; off < 256; off <<= 1) {
        int v = (t >= off) ? scanbuf[t - off] : 0;
        __syncthreads();
        scanbuf[t] += v;
        __syncthreads();
    }
    int excl = scanbuf[t] - pair;
    if (b0 < NBc) lstart[b0] = excl;
    if (b1 < NBc) lstart[b1] = excl + h0;
    if (b == 0 && t == 255) row_ptr[N] = scanbuf[255];
    __syncthreads();

    int n0 = b * NPB;
    int nb = N - n0; if (nb > NPB) nb = NPB;
    int ec = gcnt[b * CPAD];
    int bb = lstart[b];
    const unsigned int* st = staging + (size_t)b * BCAP;

    if (t < NPB) hist[t] = 0;
    __syncthreads();
    for (int i = t; i < ec; i += 256)
        atomicAdd(&hist[(st[i] >> 16) & (NPB - 1)], 1);
    __syncthreads();

    int v = (t < NPB) ? hist[t] : 0;
    if (t < NPB) scn[t] = v;
    __syncthreads();
    for (int off = 1; off < NPB; off <<= 1) {
        int u = (t >= off && t < NPB) ? scn[t - off] : 0;
        __syncthreads();
        if (t < NPB) scn[t] += u;
        __syncthreads();
    }
    if (t < NPB) hist[t] = scn[t] - v;
    if (t < nb) row_ptr[n0 + t] = bb + (scn[t] - v);
    __syncthreads();

    for (int i = t; i < ec; i += 256) {
        unsigned int pk = st[i];
        int p = atomicAdd(&hist[(pk >> 16) & (NPB - 1)], 1);
        adj[bb + p] = (int)(pk & 0xffffu);
    }
}

// ---------------- fused agg (+bias+relu) -> LDS tile -> GEMM ----------------
// Block = 128 nodes. Phase 1: 4 waves x 32 nodes, 2-node interleaved gather
// pipeline (32 loads in flight) + adj prefetch; result tile (128 x 128 bf16)
// in LDS. Phase 2: MFMA from LDS vs Wl/Wr, store CLout/CRout.
// slabsPerSide: 2 -> Dout=128 (layer 1), 1 -> Dout=64 (layer 2).

__global__ __launch_bounds__(256) void agg_gemm_kernel(
        const unsigned short* __restrict__ CLin, const unsigned short* __restrict__ CRin,
        const int* __restrict__ row_ptr, const int* __restrict__ adj,
        const float* __restrict__ bias,
        const unsigned short* __restrict__ Wl, const unsigned short* __restrict__ Wr,
        unsigned short* __restrict__ CLout, unsigned short* __restrict__ CRout,
        int N, int E, int ldOut, int slabsPerSide) {
    __shared__ unsigned int HsU[128 * HS_STRIDE_U32];   // 34.8 KB

    int wave = threadIdx.x >> 6;
    int lane = threadIdx.x & 63;
    int base = blockIdx.x * 128 + wave * 32;

    // ---- phase 1: aggregate 32 nodes (2-way interleave) ----
    int rpidx = base + lane; if (rpidx > N) rpidx = N;
    int rp = row_ptr[rpidx];      // lanes 0..33 used via shfl

    auto ldadj = [&](int b, int e_) {
        int cnt = e_ - b;
        int ll = lane; if (ll > cnt - 1) ll = cnt - 1; if (ll < 0) ll = 0;
        int ai = b + ll; if (ai > E - 1) ai = E - 1; if (ai < 0) ai = 0;
        return adj[ai];
    };

    int begA = __shfl(rp, 0), endA = __shfl(rp, 1);
    int begB = __shfl(rp, 1), endB = __shfl(rp, 2);
    int adjA = ldadj(begA, endA);
    int adjB = ldadj(begB, endB);

    for (int k = 0; k < 32; k += 2) {
        int bA = begA, eA = endA, curA = adjA;
        int bB = begB, eB = endB, curB = adjB;
        if (k + 2 < 32) {
            begA = __shfl(rp, k + 2); endA = __shfl(rp, k + 3);
            begB = __shfl(rp, k + 3); endB = __shfl(rp, k + 4);
            adjA = ldadj(begA, endA);
            adjB = ldadj(begB, endB);
        }

        float sxA[4] = {}, syA[4] = {}, sxB[4] = {}, syB[4] = {};
        int cA = eA - bA; if (cA > 64) cA = 64;
        int cB = eB - bB; if (cB > 64) cB = 64;
        int c1A = cA - 1, c1B = cB - 1;
        int cmax = cA > cB ? cA : cB;

        for (int i = 0; i < cmax; i += 16) {
            unsigned int vA[16], vB[16];
            if (i < cA) {
#pragma unroll
                for (int j = 0; j < 16; ++j) {
                    int tt = i + j; if (tt > c1A) tt = c1A;
                    int s = __shfl(curA, tt);
                    vA[j] = ((const unsigned int*)(CLin + (size_t)s * 128))[lane];
                }
            }
            if (i < cB) {
#pragma unroll
                for (int j = 0; j < 16; ++j) {
                    int tt = i + j; if (tt > c1B) tt = c1B;
                    int s = __shfl(curB, tt);
                    vB[j] = ((const unsigned int*)(CLin + (size_t)s * 128))[lane];
                }
            }
            if (i < cA) {
                int rem = cA - i;
#pragma unroll
                for (int j = 0; j < 16; ++j) {
                    float m = (j < rem) ? 1.f : 0.f;
                    sxA[j & 3] += m * bf2f(vA[j] & 0xffffu);
                    syA[j & 3] += m * bf2f(vA[j] >> 16);
                }
            }
            if (i < cB) {
                int rem = cB - i;
#pragma unroll
                for (int j = 0; j < 16; ++j) {
                    float m = (j < rem) ? 1.f : 0.f;
                    sxB[j & 3] += m * bf2f(vB[j] & 0xffffu);
                    syB[j & 3] += m * bf2f(vB[j] >> 16);
                }
            }
        }

        // ultra-rare tail (deg > 64), per node, order-preserving
        for (int half2 = 0; half2 < 2; ++half2) {
            int bb_ = half2 ? bB : bA, ee_ = half2 ? eB : eA;
            float* sx = half2 ? sxB : sxA;
            float* sy = half2 ? syB : syA;
            int e = bb_ + 64;
            while (e < ee_) {
                int cnt = ee_ - e; if (cnt > 64) cnt = 64;
                int c1 = cnt - 1;
                int ll = lane > c1 ? c1 : lane;
                int myidx = adj[e + ll];
                for (int i = 0; i < cnt; i += 16) {
                    int rem = cnt - i;
                    unsigned int v[16];
#pragma unroll
                    for (int j = 0; j < 16; ++j) {
                        int tt = i + j; if (tt > c1) tt = c1;
                        int s = __shfl(myidx, tt);
                        v[j] = ((const unsigned int*)(CLin + (size_t)s * 128))[lane];
                    }
#pragma unroll
                    for (int j = 0; j < 16; ++j) {
                        float m = (j < rem) ? 1.f : 0.f;
                        sx[j & 3] += m * bf2f(v[j] & 0xffffu);
                        sy[j & 3] += m * bf2f(v[j] >> 16);
                    }
                }
                e += cnt;
            }
        }

        float2 bb2 = ((const float2*)bias)[lane];
#pragma unroll
        for (int half2 = 0; half2 < 2; ++half2) {
            int node = base + k + half2;
            float fx, fy; int deg;
            if (half2 == 0) {
                fx = (sxA[0] + sxA[1]) + (sxA[2] + sxA[3]);
                fy = (syA[0] + syA[1]) + (syA[2] + syA[3]);
                deg = eA - bA;
            } else {
                fx = (sxB[0] + sxB[1]) + (sxB[2] + sxB[3]);
                fy = (syB[0] + syB[1]) + (syB[2] + syB[3]);
                deg = eB - bB;
            }
            unsigned int pk = 0;
            if (node < N) {
                float inv = 1.0f / (float)(deg > 1 ? deg : 1);
                unsigned int rv = ((const unsigned int*)(CRin + (size_t)node * 128))[lane];
                float ox = fmaxf(fx * inv + bb2.x + bf2f(rv & 0xffffu), 0.f);
                float oy = fmaxf(fy * inv + bb2.y + bf2f(rv >> 16), 0.f);
                pk = (unsigned int)f2bf(ox) | ((unsigned int)f2bf(oy) << 16);
            }
            HsU[(size_t)(wave * 32 + k + half2) * HS_STRIDE_U32 + lane] = pk;
        }
    }

    __syncthreads();

    // ---- phase 2: GEMM from LDS tile ----
    int l15 = lane & 15, quad = lane >> 4;
    int slabId, rowOff, passes;
    if (slabsPerSide == 2) { slabId = wave; rowOff = 0; passes = 4; }
    else                   { slabId = wave >> 1; rowOff = (wave & 1) * 64; passes = 2; }
    const unsigned short* W;
    unsigned short* Cout;
    int slab;
    if (slabId < slabsPerSide) { W = Wl; Cout = CLout; slab = slabId; }
    else                       { W = Wr; Cout = CRout; slab = slabId - slabsPerSide; }
    int wrow0 = slab * 64, col0 = slab * 64;
    int m0 = blockIdx.x * 128;
    const unsigned short* HsB = (const unsigned short*)HsU;

    for (int p = 0; p < passes; ++p) {
        int ml = rowOff + p * 32;
        f32x4 acc[2][4] = {};
#pragma unroll
        for (int ks = 0; ks < 4; ++ks) {
            int vidx = ks * 4 + quad;
            bf16x8 a0 = *(const bf16x8*)(HsB + (size_t)(ml + l15) * (HS_STRIDE_U32 * 2) + vidx * 8);
            bf16x8 a1 = *(const bf16x8*)(HsB + (size_t)(ml + 16 + l15) * (HS_STRIDE_U32 * 2) + vidx * 8);
#pragma unroll
            for (int j = 0; j < 4; ++j) {
                const bf16x8* B = (const bf16x8*)(W + (size_t)(wrow0 + j * 16 + l15) * 128);
                bf16x8 b = B[vidx];
                acc[0][j] = __builtin_amdgcn_mfma_f32_16x16x32_bf16(a0, b, acc[0][j], 0, 0, 0);
                acc[1][j] = __builtin_amdgcn_mfma_f32_16x16x32_bf16(a1, b, acc[1][j], 0, 0, 0);
            }
        }
#pragma unroll
        for (int i = 0; i < 2; ++i)
#pragma unroll
            for (int j = 0; j < 4; ++j)
#pragma unroll
                for (int r = 0; r < 4; ++r) {
                    int row = m0 + ml + i * 16 + quad * 4 + r;
                    if (row < N) {
                        int col = col0 + j * 16 + l15;
                        Cout[(size_t)row * ldOut + col] = f2bf(acc[i][j][r]);
                    }
                }
    }
}

// ---------------- Final layer: gathers + fused log_softmax (unchanged) ----------------

__global__ __launch_bounds__(256) void final_kernel(const unsigned short* __restrict__ CL,
                                                    const unsigned short* __restrict__ CR,
                                                    const int* __restrict__ row_ptr,
                                                    const int* __restrict__ adj,
                                                    const float* __restrict__ bias,
                                                    float* __restrict__ out, int N) {
    int node = (int)((blockIdx.x * blockDim.x + threadIdx.x) >> 6);
    int lane = threadIdx.x & 63;
    if (node >= N) return;
    int beg = row_ptr[node], end = row_ptr[node + 1];
    float a[4] = {};

    int e = beg;
    while (e < end) {
        int cnt = end - e; if (cnt > 64) cnt = 64;
        int c1 = cnt - 1;
        int ll = lane > c1 ? c1 : lane;
        int myidx = adj[e + ll];

        for (int i = 0; i < cnt; i += 16) {
            int rem = cnt - i;
            float v[16];
#pragma unroll
            for (int j = 0; j < 16; ++j) {
                int tt = i + j; if (tt > c1) tt = c1;
                int s = __shfl(myidx, tt);
                v[j] = bf2f((unsigned int)CL[(size_t)s * 64 + lane]);
            }
#pragma unroll
            for (int j = 0; j < 16; ++j) {
                float m = (j < rem) ? 1.f : 0.f;
                a[j & 3] += m * v[j];
            }
        }
        e += cnt;
    }

    float sum = (a[0] + a[1]) + (a[2] + a[3]);
    int deg = end - beg;
    float inv = 1.0f / (float)(deg > 1 ? deg : 1);
    float u = sum * inv + bias[lane] + bf2f((unsigned int)CR[(size_t)node * 64 + lane]);

    float m = u;
#pragma unroll
    for (int off = 32; off > 0; off >>= 1) m = fmaxf(m, __shfl_xor(m, off));
    float ex = __expf(u - m);
    float se = ex;
#pragma unroll
    for (int off = 32; off > 0; off >>= 1) se += __shfl_xor(se, off);
    out[(size_t)node * 64 + lane] = (u - m) - __logf(se);
}

// ---------------- Launch ----------------

extern "C" void kernel_launch(void* const* d_in, const int* in_sizes, int n_in,
                              void* d_out, int out_size, void* d_ws, size_t ws_size,
                              hipStream_t stream) {
    const float* x   = (const float*)d_in[0];
    const int*   ei  = (const int*)d_in[1];
    const float* Wl0 = (const float*)d_in[2];
    const float* bl0 = (const float*)d_in[3];
    const float* Wr0 = (const float*)d_in[4];
    const float* Wl1 = (const float*)d_in[5];
    const float* bl1 = (const float*)d_in[6];
    const float* Wr1 = (const float*)d_in[7];
    const float* Wl2 = (const float*)d_in[8];
    const float* bl2 = (const float*)d_in[9];
    const float* Wr2 = (const float*)d_in[10];
    float* out = (float*)d_out;

    const int N  = in_sizes[0] / 128;   // 50000
    const int E  = in_sizes[1] / 2;     // 800000
    const int NB = (N + NPB - 1) / NPB; // 391

    char* ws = (char*)d_ws;
    auto alloc = [&](size_t bytes) {
        char* p = ws;
        ws += (bytes + 255) & ~(size_t)255;
        return p;
    };
    int*   row_ptr = (int*)alloc((size_t)(N + 1) * 4);
    int*   adj     = (int*)alloc((size_t)E * 4);
    int*   gcnt    = (int*)alloc((size_t)NB * CPAD * 4);
    unsigned int* staging = (unsigned int*)alloc((size_t)NB * BCAP * 4);
    unsigned short* xbf = (unsigned short*)alloc((size_t)N * 128 * 2);
    unsigned short* wbf = (unsigned short*)alloc((size_t)81920 * 2);
    unsigned short* CL0 = (unsigned short*)alloc((size_t)N * 128 * 2);
    unsigned short* CR0 = (unsigned short*)alloc((size_t)N * 128 * 2);
    unsigned short* CL1 = (unsigned short*)alloc((size_t)N * 128 * 2);
    unsigned short* CR1 = (unsigned short*)alloc((size_t)N * 128 * 2);
    unsigned short* CL2 = (unsigned short*)alloc((size_t)N * 64 * 2);
    unsigned short* CR2 = (unsigned short*)alloc((size_t)N * 64 * 2);

    const int* dstp = ei;       // edge_index row 0 = dst
    const int* srcp = ei + E;   // edge_index row 1 = src

    hipMemsetAsync(gcnt, 0, (size_t)NB * CPAD * 4, stream);

    // K1: fused distribute + casts
    int distBlocks = (E + EPB - 1) / EPB;            // 98
    int xpairs = N * 64;
    int castBlocks = (xpairs + 255) / 256 + 160;
    dist_cast_kernel<<<distBlocks + castBlocks, 256, 0, stream>>>(
        dstp, srcp, gcnt, staging, E, NB,
        x, Wl0, Wr0, Wl1, Wr1, Wl2, Wr2, xbf, wbf, xpairs, distBlocks);

    unsigned short* wl0 = wbf;
    unsigned short* wr0 = wbf + 16384;
    unsigned short* wl1 = wbf + 32768;
    unsigned short* wr1 = wbf + 49152;
    unsigned short* wl2 = wbf + 65536;
    unsigned short* wr2 = wbf + 73728;

    dim3 blk(256);
    int gemmRows = (N + 127) / 128;     // 391
    int aggBlocks = (N * 64 + 255) / 256;

    // K2: build || gemm0
    build_gemm0_kernel<<<NB + gemmRows * 4, blk, 0, stream>>>(
        staging, gcnt, row_ptr, adj, N, NB, xbf, wl0, wr0, CL0, CR0, gemmRows);

    // K3: agg0 (+bl0+relu) fused with gemm1 -> CL1/CR1
    agg_gemm_kernel<<<gemmRows, blk, 0, stream>>>(
        CL0, CR0, row_ptr, adj, bl0, wl1, wr1, CL1, CR1, N, E, 128, 2);

    // K4: agg1 (+bl1+relu) fused with gemm2 -> CL2/CR2 (Dout=64)
    agg_gemm_kernel<<<gemmRows, blk, 0, stream>>>(
        CL1, CR1, row_ptr, adj, bl1, wl2, wr2, CL2, CR2, N, E, 64, 1);

    // K5: final aggregation + bl2 + log_softmax
    final_kernel<<<aggBlocks, blk, 0, stream>>>(CL2, CR2, row_ptr, adj, bl2, out, N);
}

// Round 10
// 295.837 us; speedup vs baseline: 1.0942x; 1.0942x over previous
//
#include <hip/hip_runtime.h>
#include <hip/hip_bf16.h>

// GraphSAGE 3-layer forward, MI355X. Round 10 (base = R8, best @278us):
//  - R9 agg+gemm fusion reverted (391-block fused grid -> 1.5 waves/SIMD starved
//    the gather; occupancy 14% -> 82us).
//  - Gather payloads (CL*) now fp8 e4m3 (x16 scale): 256B->128B rows (4->2 L2
//    lines per gather), final layer 128B->64B (1 line). Agg is fabric
//    transaction-rate bound (unroll-16 + footprint-split both neutral), so
//    halving lines/gather should ~halve agg time. Self path/bias/accum stay
//    bf16/fp32; only gathered values quantized (error /~sqrt(deg)).

typedef __attribute__((ext_vector_type(8))) short bf16x8;
typedef __attribute__((ext_vector_type(4))) float f32x4;

#define NPB 128            // nodes per bucket (bucket = dst >> 7)
#define BCAP 2560          // per-bucket staging capacity (mean 2048, sd ~45)
#define EPB 8192           // edges per distribute block
#define EPT 32             // edges per thread (256 thr)
#define CPAD 16            // global counter stride in ints (64B line each)

__device__ __forceinline__ unsigned short f2bf(float f) {
    unsigned int u = __builtin_bit_cast(unsigned int, f);
    u += 0x7fffu + ((u >> 16) & 1u);           // round-to-nearest-even
    return (unsigned short)(u >> 16);
}
__device__ __forceinline__ float bf2f(unsigned int bits16) {
    return __builtin_bit_cast(float, bits16 << 16);
}

// encode 16*x as fp8 e4m3 (RNE, subnormals flushed, saturate 448)
__device__ __forceinline__ unsigned char f2fp8s(float x) {
    float xs = x * 16.0f;
    unsigned int u = __builtin_bit_cast(unsigned int, xs);
    unsigned int a = u & 0x7fffffffu;
    if (a < 0x3C800000u) return 0;                     // |16x| < 2^-6 -> 0
    unsigned int r = a + 0x7ffffu + ((a >> 20) & 1u);  // RNE to 3-bit mantissa
    unsigned int em = (r >> 20) - 960u;                // e8*8 + m  (e32-120)<<3|m
    if (em > 126u) em = 126u;                          // clamp to 448
    return (unsigned char)(((u >> 24) & 0x80u) | em);
}
// decode: raw = bitcast(sign<<31 | b7<<20); true value = raw * 2^116
// (2^116 is folded into the accumulate mask constant; raw is normal f32 or 0)

// ---------------- fused: CSR phase A (distribute) + bf16 casts ----------------
// staging word: dst << 16 | src (both < 65536). bucket = word >> 23 (= dst>>7).

__global__ __launch_bounds__(256) void dist_cast_kernel(
        const int* __restrict__ dst, const int* __restrict__ srcv,
        int* __restrict__ gcnt, unsigned int* __restrict__ staging, int E, int NBc,
        const float* __restrict__ x,
        const float* p0, const float* p1, const float* p2,
        const float* p3, const float* p4, const float* p5,
        unsigned short* __restrict__ xbf, unsigned short* __restrict__ wbf,
        int xpairs, int distBlocks) {
    __shared__ unsigned int stage[EPB];      // 32KB
    __shared__ int hist[400];
    __shared__ int lstart[400];
    __shared__ int gbase[400];
    __shared__ int scanbuf[256];
    int t = threadIdx.x;

    if (blockIdx.x >= distBlocks) {
        int bid = blockIdx.x - distBlocks;
        int xblocks = (xpairs + 255) / 256;
        if (bid < xblocks) {
            int i = bid * 256 + t;
            if (i < xpairs) {
                float2 v = ((const float2*)x)[i];
                unsigned int p = (unsigned int)f2bf(v.x) | ((unsigned int)f2bf(v.y) << 16);
                ((unsigned int*)xbf)[i] = p;
            }
        } else {
            int w = (bid - xblocks) * 256 + t;
            if (w < 40960) {
                const float* src;
                int local;
                if      (w < 8192)  { src = p0; local = w; }
                else if (w < 16384) { src = p1; local = w - 8192; }
                else if (w < 24576) { src = p2; local = w - 16384; }
                else if (w < 32768) { src = p3; local = w - 24576; }
                else if (w < 36864) { src = p4; local = w - 32768; }
                else                { src = p5; local = w - 36864; }
                float2 v = ((const float2*)src)[local];
                unsigned int p = (unsigned int)f2bf(v.x) | ((unsigned int)f2bf(v.y) << 16);
                ((unsigned int*)wbf)[w] = p;
            }
        }
        return;
    }

    int e0 = blockIdx.x * EPB;
    unsigned int w[EPT];

    for (int b = t; b < NBc + 1; b += 256) hist[b] = 0;
    __syncthreads();

#pragma unroll
    for (int i = 0; i < EPT; ++i) {
        int e = e0 + i * 256 + t;
        unsigned int word = 0xFFFFFFFFu;
        if (e < E) word = ((unsigned int)dst[e] << 16) | (unsigned int)srcv[e];
        w[i] = word;
        int b = (int)(word >> 23); if (b > NBc) b = NBc;
        atomicAdd(&hist[b], 1);
    }
    __syncthreads();

    int b0 = 2 * t, b1 = 2 * t + 1;
    int h0 = (b0 <= NBc) ? hist[b0] : 0;
    int h1 = (b1 <= NBc) ? hist[b1] : 0;
    int pair = h0 + h1;
    scanbuf[t] = pair;
    __syncthreads();
    for (int off = 1; off < 256; off <<= 1) {
        int v = (t >= off) ? scanbuf[t - off] : 0;
        __syncthreads();
        scanbuf[t] += v;
        __syncthreads();
    }
    int excl = scanbuf[t] - pair;
    if (b0 <= NBc) lstart[b0] = excl;
    if (b1 <= NBc) lstart[b1] = excl + h0;
    __syncthreads();

    for (int b = t; b < NBc; b += 256) {
        int h = hist[b];
        gbase[b] = h ? atomicAdd(&gcnt[b * CPAD], h) : 0;
    }
    for (int b = t; b < NBc + 1; b += 256) hist[b] = lstart[b];
    __syncthreads();

#pragma unroll
    for (int i = 0; i < EPT; ++i) {
        unsigned int word = w[i];
        int b = (int)(word >> 23); if (b > NBc) b = NBc;
        int p = atomicAdd(&hist[b], 1);
        stage[p] = word;
    }
    __syncthreads();

    int total = lstart[NBc];
    for (int i = t; i < total; i += 256) {
        unsigned int word = stage[i];
        int b = (int)(word >> 23);
        int gpos = gbase[b] + (i - lstart[b]);
        staging[(size_t)b * BCAP + gpos] = word;
    }
}

// ---------------- GEMM tile: CL (fp8, gathered later) / CR (bf16, self) ----------------
// H: N x 128 bf16. Wl/Wr: Dout x 128 bf16. CL: N x Dout fp8. CR: N x Dout bf16.

__device__ __forceinline__ void gemm_tile(const unsigned short* __restrict__ H,
                                          const unsigned short* __restrict__ Wl,
                                          const unsigned short* __restrict__ Wr,
                                          unsigned char* __restrict__ CL,
                                          unsigned short* __restrict__ CR,
                                          int bx, int y, int half, int ldC, int N) {
    int wave = threadIdx.x >> 6;
    int lane = threadIdx.x & 63;
    int l15 = lane & 15, quad = lane >> 4;
    int left = (y < half);
    const unsigned short* W = left ? Wl : Wr;
    int slab = left ? y : y - half;
    int wrow0 = slab * 64;
    int col0 = slab * 64;
    int m0 = bx * 128 + wave * 32;

    int r0 = m0 + l15;      if (r0 > N - 1) r0 = N - 1;
    int r1 = m0 + 16 + l15; if (r1 > N - 1) r1 = N - 1;
    const bf16x8* A0 = (const bf16x8*)(H + (size_t)r0 * 128);
    const bf16x8* A1 = (const bf16x8*)(H + (size_t)r1 * 128);

    f32x4 acc[2][4] = {};
#pragma unroll
    for (int ks = 0; ks < 4; ++ks) {
        int vidx = ks * 4 + quad;
        bf16x8 a0 = A0[vidx];
        bf16x8 a1 = A1[vidx];
#pragma unroll
        for (int j = 0; j < 4; ++j) {
            const bf16x8* B = (const bf16x8*)(W + (size_t)(wrow0 + j * 16 + l15) * 128);
            bf16x8 b = B[vidx];
            acc[0][j] = __builtin_amdgcn_mfma_f32_16x16x32_bf16(a0, b, acc[0][j], 0, 0, 0);
            acc[1][j] = __builtin_amdgcn_mfma_f32_16x16x32_bf16(a1, b, acc[1][j], 0, 0, 0);
        }
    }

#pragma unroll
    for (int i = 0; i < 2; ++i)
#pragma unroll
        for (int j = 0; j < 4; ++j)
#pragma unroll
            for (int r = 0; r < 4; ++r) {
                int row = m0 + i * 16 + quad * 4 + r;
                if (row < N) {
                    int col = col0 + j * 16 + l15;
                    if (left) CL[(size_t)row * ldC + col] = f2fp8s(acc[i][j][r]);
                    else      CR[(size_t)row * ldC + col] = f2bf(acc[i][j][r]);
                }
            }
}

__global__ __launch_bounds__(256) void gemm_kernel(const unsigned short* __restrict__ H,
                                                   const unsigned short* __restrict__ Wl,
                                                   const unsigned short* __restrict__ Wr,
                                                   unsigned char* __restrict__ CL,
                                                   unsigned short* __restrict__ CR,
                                                   int half, int ldC, int N) {
    gemm_tile(H, Wl, Wr, CL, CR, blockIdx.x, blockIdx.y, half, ldC, N);
}

// ---------------- merged: CSR phase B (build) || gemm0 ----------------

__global__ __launch_bounds__(256) void build_gemm0_kernel(
        const unsigned int* __restrict__ staging, const int* __restrict__ gcnt,
        int* __restrict__ row_ptr, int* __restrict__ adj, int N, int NBc,
        const unsigned short* __restrict__ xbf,
        const unsigned short* __restrict__ wl0, const unsigned short* __restrict__ wr0,
        unsigned char* __restrict__ CL, unsigned short* __restrict__ CR,
        int gemmRows) {
    __shared__ int lstart[400];
    __shared__ int scanbuf[256];
    __shared__ int hist[NPB];
    __shared__ int scn[NPB];
    int t = threadIdx.x;

    if (blockIdx.x >= (unsigned)NBc) {
        int g = blockIdx.x - NBc;
        gemm_tile(xbf, wl0, wr0, CL, CR, g % gemmRows, g / gemmRows, 2, 128, N);
        return;
    }
    int b = blockIdx.x;

    int b0 = 2 * t, b1 = 2 * t + 1;
    int h0 = (b0 < NBc) ? gcnt[b0 * CPAD] : 0;
    int h1 = (b1 < NBc) ? gcnt[b1 * CPAD] : 0;
    int pair = h0 + h1;
    scanbuf[t] = pair;
    __syncthreads();
    for (int off = 1; off < 256; off <<= 1) {
        int v = (t >= off) ? scanbuf[t - off] : 0;
        __syncthreads();
        scanbuf[t] += v;
        __syncthreads();
    }
    int excl = scanbuf[t] - pair;
    if (b0 < NBc) lstart[b0] = excl;
    if (b1 < NBc) lstart[b1] = excl + h0;
    if (b == 0 && t == 255) row_ptr[N] = scanbuf[255];   // total == E
    __syncthreads();

    int n0 = b * NPB;
    int nb = N - n0; if (nb > NPB) nb = NPB;
    int ec = gcnt[b * CPAD];
    int bb = lstart[b];
    const unsigned int* st = staging + (size_t)b * BCAP;

    if (t < NPB) hist[t] = 0;
    __syncthreads();
    for (int i = t; i < ec; i += 256)
        atomicAdd(&hist[(st[i] >> 16) & (NPB - 1)], 1);
    __syncthreads();

    int v = (t < NPB) ? hist[t] : 0;
    if (t < NPB) scn[t] = v;
    __syncthreads();
    for (int off = 1; off < NPB; off <<= 1) {
        int u = (t >= off && t < NPB) ? scn[t - off] : 0;
        __syncthreads();
        if (t < NPB) scn[t] += u;
        __syncthreads();
    }
    if (t < NPB) hist[t] = scn[t] - v;
    if (t < nb) row_ptr[n0 + t] = bb + (scn[t] - v);
    __syncthreads();

    for (int i = t; i < ec; i += 256) {
        unsigned int pk = st[i];
        int p = atomicAdd(&hist[(pk >> 16) & (NPB - 1)], 1);
        adj[bb + p] = (int)(pk & 0xffffu);
    }
}

// ---------------- Aggregation (layers 0,1): wave/node, fp8 gathers ----------------
// CL: N x 128 fp8 (gathered, 128B rows = 2 lines). CR: N x 128 bf16 (self).
// lane reads ushort = dims 2l, 2l+1. Decode: bitcast + mask-folded 2^116 scale.

__global__ __launch_bounds__(256) void agg_relu_kernel(const unsigned char* __restrict__ CL,
                                                       const unsigned short* __restrict__ CR,
                                                       const int* __restrict__ row_ptr,
                                                       const int* __restrict__ adj,
                                                       const float* __restrict__ bias,
                                                       unsigned short* __restrict__ hout, int N) {
    int node = (int)((blockIdx.x * blockDim.x + threadIdx.x) >> 6);
    int lane = threadIdx.x & 63;
    if (node >= N) return;
    int beg = row_ptr[node], end = row_ptr[node + 1];
    float sx[4] = {}, sy[4] = {};

    int e = beg;
    while (e < end) {
        int cnt = end - e; if (cnt > 64) cnt = 64;
        int c1 = cnt - 1;
        int ll = lane > c1 ? c1 : lane;
        int myidx = adj[e + ll];                 // one coalesced load, clamped

        for (int i = 0; i < cnt; i += 16) {
            int rem = cnt - i;
            unsigned int v[16];
#pragma unroll
            for (int j = 0; j < 16; ++j) {
                int tt = i + j; if (tt > c1) tt = c1;
                int s = __shfl(myidx, tt);
                v[j] = ((const unsigned short*)(CL + (size_t)s * 128))[lane];
            }
#pragma unroll
            for (int j = 0; j < 16; ++j) {
                float mv = (j < rem) ? 0x1p116f : 0.f;   // fp8 scale 2^116 folded in
                float r0 = __builtin_bit_cast(float, ((v[j] & 0x7fu) << 20) | ((v[j] & 0x80u) << 24));
                float r1 = __builtin_bit_cast(float, ((v[j] & 0x7f00u) << 12) | ((v[j] & 0x8000u) << 16));
                sx[j & 3] += mv * r0;
                sy[j & 3] += mv * r1;
            }
        }
        e += cnt;
    }

    float fx = (sx[0] + sx[1]) + (sx[2] + sx[3]);
    float fy = (sy[0] + sy[1]) + (sy[2] + sy[3]);
    int deg = end - beg;
    float inv = 1.0f / (float)(deg > 1 ? deg : 1);
    float2 bb = ((const float2*)bias)[lane];
    unsigned int rv = ((const unsigned int*)(CR + (size_t)node * 128))[lane];
    float ox = fmaxf(fx * inv + bb.x + bf2f(rv & 0xffffu), 0.f);
    float oy = fmaxf(fy * inv + bb.y + bf2f(rv >> 16), 0.f);
    unsigned int p = (unsigned int)f2bf(ox) | ((unsigned int)f2bf(oy) << 16);
    ((unsigned int*)(hout + (size_t)node * 128))[lane] = p;
}

// ---------------- Final layer: fp8 CL2 (N x 64 = 1 line/row), fused log_softmax ----------------

__global__ __launch_bounds__(256) void final_kernel(const unsigned char* __restrict__ CL,
                                                    const unsigned short* __restrict__ CR,
                                                    const int* __restrict__ row_ptr,
                                                    const int* __restrict__ adj,
                                                    const float* __restrict__ bias,
                                                    float* __restrict__ out, int N) {
    int node = (int)((blockIdx.x * blockDim.x + threadIdx.x) >> 6);
    int lane = threadIdx.x & 63;
    if (node >= N) return;
    int beg = row_ptr[node], end = row_ptr[node + 1];
    float a[4] = {};

    int e = beg;
    while (e < end) {
        int cnt = end - e; if (cnt > 64) cnt = 64;
        int c1 = cnt - 1;
        int ll = lane > c1 ? c1 : lane;
        int myidx = adj[e + ll];

        for (int i = 0; i < cnt; i += 16) {
            int rem = cnt - i;
            unsigned int v[16];
#pragma unroll
            for (int j = 0; j < 16; ++j) {
                int tt = i + j; if (tt > c1) tt = c1;
                int s = __shfl(myidx, tt);
                v[j] = CL[(size_t)s * 64 + lane];
            }
#pragma unroll
            for (int j = 0; j < 16; ++j) {
                float mv = (j < rem) ? 0x1p116f : 0.f;
                float r = __builtin_bit_cast(float, ((v[j] & 0x7fu) << 20) | ((v[j] & 0x80u) << 24));
                a[j & 3] += mv * r;
            }
        }
        e += cnt;
    }

    float sum = (a[0] + a[1]) + (a[2] + a[3]);
    int deg = end - beg;
    float inv = 1.0f / (float)(deg > 1 ? deg : 1);
    float u = sum * inv + bias[lane] + bf2f((unsigned int)CR[(size_t)node * 64 + lane]);

    float m = u;
#pragma unroll
    for (int off = 32; off > 0; off >>= 1) m = fmaxf(m, __shfl_xor(m, off));
    float ex = __expf(u - m);
    float se = ex;
#pragma unroll
    for (int off = 32; off > 0; off >>= 1) se += __shfl_xor(se, off);
    out[(size_t)node * 64 + lane] = (u - m) - __logf(se);
}

// ---------------- Launch ----------------

extern "C" void kernel_launch(void* const* d_in, const int* in_sizes, int n_in,
                              void* d_out, int out_size, void* d_ws, size_t ws_size,
                              hipStream_t stream) {
    const float* x   = (const float*)d_in[0];
    const int*   ei  = (const int*)d_in[1];
    const float* Wl0 = (const float*)d_in[2];
    const float* bl0 = (const float*)d_in[3];
    const float* Wr0 = (const float*)d_in[4];
    const float* Wl1 = (const float*)d_in[5];
    const float* bl1 = (const float*)d_in[6];
    const float* Wr1 = (const float*)d_in[7];
    const float* Wl2 = (const float*)d_in[8];
    const float* bl2 = (const float*)d_in[9];
    const float* Wr2 = (const float*)d_in[10];
    float* out = (float*)d_out;

    const int N  = in_sizes[0] / 128;   // 50000
    const int E  = in_sizes[1] / 2;     // 800000
    const int NB = (N + NPB - 1) / NPB; // 391

    char* ws = (char*)d_ws;
    auto alloc = [&](size_t bytes) {
        char* p = ws;
        ws += (bytes + 255) & ~(size_t)255;
        return p;
    };
    int*   row_ptr = (int*)alloc((size_t)(N + 1) * 4);
    int*   adj     = (int*)alloc((size_t)E * 4);
    int*   gcnt    = (int*)alloc((size_t)NB * CPAD * 4);
    unsigned int* staging = (unsigned int*)alloc((size_t)NB * BCAP * 4);
    unsigned short* xbf = (unsigned short*)alloc((size_t)N * 128 * 2);
    unsigned short* wbf = (unsigned short*)alloc((size_t)81920 * 2);
    unsigned char*  CLb = (unsigned char*)alloc((size_t)N * 128);      // fp8 gather payload
    unsigned short* CRb = (unsigned short*)alloc((size_t)N * 128 * 2); // bf16 self path
    unsigned short* hA  = (unsigned short*)alloc((size_t)N * 128 * 2);
    unsigned short* hB  = (unsigned short*)alloc((size_t)N * 128 * 2);

    const int* dstp = ei;       // edge_index row 0 = dst
    const int* srcp = ei + E;   // edge_index row 1 = src

    hipMemsetAsync(gcnt, 0, (size_t)NB * CPAD * 4, stream);

    // K1: fused distribute + casts
    int distBlocks = (E + EPB - 1) / EPB;            // 98
    int xpairs = N * 64;
    int castBlocks = (xpairs + 255) / 256 + 160;
    dist_cast_kernel<<<distBlocks + castBlocks, 256, 0, stream>>>(
        dstp, srcp, gcnt, staging, E, NB,
        x, Wl0, Wr0, Wl1, Wr1, Wl2, Wr2, xbf, wbf, xpairs, distBlocks);

    unsigned short* wl0 = wbf;
    unsigned short* wr0 = wbf + 16384;
    unsigned short* wl1 = wbf + 32768;
    unsigned short* wr1 = wbf + 49152;
    unsigned short* wl2 = wbf + 65536;
    unsigned short* wr2 = wbf + 73728;

    dim3 blk(256);
    int gemmRows = (N + 127) / 128;     // 391
    int aggBlocks = (N * 64 + 255) / 256;

    // K2: build || gemm0
    build_gemm0_kernel<<<NB + gemmRows * 4, blk, 0, stream>>>(
        staging, gcnt, row_ptr, adj, N, NB, xbf, wl0, wr0, CLb, CRb, gemmRows);

    // K3: agg0
    agg_relu_kernel<<<aggBlocks, blk, 0, stream>>>(CLb, CRb, row_ptr, adj, bl0, hA, N);
    // K4: gemm1
    gemm_kernel<<<dim3(gemmRows, 4), blk, 0, stream>>>(hA, wl1, wr1, CLb, CRb, 2, 128, N);
    // K5: agg1
    agg_relu_kernel<<<aggBlocks, blk, 0, stream>>>(CLb, CRb, row_ptr, adj, bl1, hB, N);
    // K6: gemm2 (Dout=64)
    gemm_kernel<<<dim3(gemmRows, 2), blk, 0, stream>>>(hB, wl2, wr2, CLb, CRb, 1, 64, N);
    // K7: final + log_softmax
    final_kernel<<<aggBlocks, blk, 0, stream>>>(CLb, CRb, row_ptr, adj, bl2, out, N);
}